// Round 1
// baseline (12267.838 us; speedup 1.0000x reference)
//
#include <hip/hip_runtime.h>
#include <hip/hip_bf16.h>
#include <math.h>

typedef __bf16 bf16;
typedef __bf16 bf16x8 __attribute__((ext_vector_type(8)));
typedef __bf16 bf16x4 __attribute__((ext_vector_type(4)));
typedef float f32x4 __attribute__((ext_vector_type(4)));

#define T_LEN 512
#define BATCH 64
#define HDIM  1024
#define IDIM  512

struct Ptr12 { const float* p[12]; };
struct Ptr6  { const float* p[6];  };

// ---------------------------------------------------------------------------
// K0: transpose + fp32->bf16 convert all weight matrices.
// z 0..5  : W_h (K=1024): hr_f, hz_f, hh_f, hr_b, hz_b, hh_b  -> wt_h [n][k]
// z 6..11 : W_x (K=512):  xr_f, xz_f, xh_f, xr_b, xz_b, xh_b  -> wt_x [n][k]
// src is [K][N] row-major with N=1024 always.
// ---------------------------------------------------------------------------
__global__ __launch_bounds__(256) void transpose_convert(Ptr12 W, bf16* wt_h, bf16* wt_x) {
    int z = blockIdx.z;
    int K = (z < 6) ? HDIM : IDIM;
    const float* src = W.p[z];
    bf16* dst = (z < 6) ? (wt_h + (size_t)z * HDIM * HDIM)
                        : (wt_x + (size_t)(z - 6) * HDIM * IDIM);
    int n0 = blockIdx.x * 32;
    int k0 = blockIdx.y * 32;
    if (k0 >= K) return;
    __shared__ float tile[32][33];
    int tx = threadIdx.x & 31, ty = threadIdx.x >> 5;  // ty 0..7
#pragma unroll
    for (int i = 0; i < 32; i += 8)
        tile[ty + i][tx] = src[(size_t)(k0 + ty + i) * HDIM + n0 + tx];
    __syncthreads();
#pragma unroll
    for (int i = 0; i < 32; i += 8)
        dst[(size_t)(n0 + ty + i) * K + k0 + tx] = (bf16)tile[tx][ty + i];
}

// ---------------------------------------------------------------------------
// K0b: x fp32 -> bf16 (same [b][t][i] layout)
// ---------------------------------------------------------------------------
__global__ __launch_bounds__(256) void convert_x(const float* __restrict__ x, bf16* __restrict__ xbf) {
    size_t i = ((size_t)blockIdx.x * blockDim.x + threadIdx.x) * 4;
    float4 v = *(const float4*)(x + i);
    bf16x4 o = { (bf16)v.x, (bf16)v.y, (bf16)v.z, (bf16)v.w };
    *(bf16x4*)(xbf + i) = o;
}

// ---------------------------------------------------------------------------
// K0c: init h state (bf16) from h_prev inputs (fp32)
// ---------------------------------------------------------------------------
__global__ __launch_bounds__(256) void init_h(const float* __restrict__ hf, const float* __restrict__ hb,
                                              bf16* __restrict__ h_cur) {
    int i = blockIdx.x * blockDim.x + threadIdx.x;  // 0..65535
    h_cur[i] = (bf16)hf[i];
    h_cur[BATCH * HDIM + i] = (bf16)hb[i];
}

// ---------------------------------------------------------------------------
// K1: xproj GEMM. XP[g][t][b][n] = (x @ W_x_g)[b*T+t][n] + bias_g[n], bf16.
// grid (512, 16, 6), block 256 (4 waves). Tile 64(M) x 64(N), K=512.
// ---------------------------------------------------------------------------
__global__ __launch_bounds__(256) void xproj_gemm(const bf16* __restrict__ xbf,
                                                  const bf16* __restrict__ wt_x,
                                                  Ptr6 biases,
                                                  bf16* __restrict__ XP) {
    int g  = blockIdx.z;
    int m0 = blockIdx.x * 64;
    int n0 = blockIdx.y * 64;
    int w  = threadIdx.x >> 6;
    int l  = threadIdx.x & 63;
    int lm = l & 15, lq = l >> 4;

    const bf16* Wg    = wt_x + (size_t)g * HDIM * IDIM;
    const bf16* Abase = xbf + (size_t)(m0 + 16 * w + lm) * IDIM + lq * 8;
    const bf16* Bbase = Wg + (size_t)(n0 + lm) * IDIM + lq * 8;

    f32x4 acc[4] = {};
#pragma unroll 2
    for (int k = 0; k < IDIM; k += 32) {
        bf16x8 a = *(const bf16x8*)(Abase + k);
#pragma unroll
        for (int nt = 0; nt < 4; nt++) {
            bf16x8 b = *(const bf16x8*)(Bbase + (size_t)nt * 16 * IDIM + k);
            acc[nt] = __builtin_amdgcn_mfma_f32_16x16x32_bf16(a, b, acc[nt], 0, 0, 0);
        }
    }

    const float* bias = biases.p[g];
    int mrow = m0 + 16 * w + lq * 4;
#pragma unroll
    for (int nt = 0; nt < 4; nt++) {
        int n = n0 + nt * 16 + lm;
        float bv = bias[n];
#pragma unroll
        for (int r = 0; r < 4; r++) {
            int m = mrow + r;
            int b_ = m >> 9;       // batch
            int t  = m & 511;      // time
            XP[(((size_t)g * T_LEN + t) * BATCH + b_) * HDIM + n] = (bf16)(acc[nt][r] + bv);
        }
    }
}

// ---------------------------------------------------------------------------
// K2: phase A of one recurrence step.
// grid 256: dir(2) x batch-half gb(2) x 16-col slice s(64). block 256 (4 waves).
// wave = (mt = w&1 [16-row tile within half], gate = w>>1 [0:R, 1:Z]).
// Computes R,Z slice; writes Rh = R*h (bf16) and Z (bf16).
// ---------------------------------------------------------------------------
__global__ __launch_bounds__(256) void gru_phase_a(const bf16* __restrict__ wt_h,
                                                   const bf16* __restrict__ XP,
                                                   const bf16* __restrict__ h_cur,
                                                   bf16* __restrict__ Rh,
                                                   bf16* __restrict__ Zbuf,
                                                   int step) {
    int blk = blockIdx.x;
    int dir = blk >> 7;
    int gb  = (blk >> 6) & 1;
    int s   = blk & 63;
    int n0  = s * 16;
    int t   = dir ? (T_LEN - 1 - step) : step;

    int w = threadIdx.x >> 6, l = threadIdx.x & 63;
    int lm = l & 15, lq = l >> 4;
    int mt   = w & 1;
    int gate = w >> 1;
    int mrowA = gb * 32 + mt * 16 + lm;

    const bf16* h_d = h_cur + (size_t)dir * BATCH * HDIM;
    const bf16* Wp  = wt_h + (size_t)(dir * 3 + gate) * HDIM * HDIM + (size_t)(n0 + lm) * HDIM + lq * 8;
    const bf16* A   = h_d + (size_t)mrowA * HDIM + lq * 8;

    f32x4 acc = {};
#pragma unroll 8
    for (int k = 0; k < HDIM; k += 32) {
        bf16x8 a = *(const bf16x8*)(A + k);
        bf16x8 b = *(const bf16x8*)(Wp + k);
        acc = __builtin_amdgcn_mfma_f32_16x16x32_bf16(a, b, acc, 0, 0, 0);
    }

    const bf16* xp = XP + ((size_t)(dir * 3 + gate) * T_LEN + t) * BATCH * HDIM;
    int n = n0 + lm;
    int brow = gb * 32 + mt * 16 + lq * 4;
#pragma unroll
    for (int r = 0; r < 4; r++) {
        int b_ = brow + r;
        float pre = acc[r] + (float)xp[(size_t)b_ * HDIM + n];
        float gv = 1.0f / (1.0f + __expf(-pre));
        if (gate == 0) {
            float hv = (float)h_d[(size_t)b_ * HDIM + n];
            Rh[(size_t)dir * BATCH * HDIM + (size_t)b_ * HDIM + n] = (bf16)(gv * hv);
        } else {
            Zbuf[(size_t)dir * BATCH * HDIM + (size_t)b_ * HDIM + n] = (bf16)gv;
        }
    }
}

// ---------------------------------------------------------------------------
// K3: phase B of one recurrence step.
// grid 256: dir(2) x gb(2) x s(64). block 128 (2 waves = 2 row tiles).
// h_til = tanh(Rh @ W_hh + xh); h_new = Z*h_til + (1-Z)*h  (in-place h update)
// Also writes fp32 output at [b][t][dir*1024 + n].
// ---------------------------------------------------------------------------
__global__ __launch_bounds__(128) void gru_phase_b(const bf16* __restrict__ wt_h,
                                                   const bf16* __restrict__ XP,
                                                   const bf16* __restrict__ Rh,
                                                   const bf16* __restrict__ Zbuf,
                                                   bf16* __restrict__ h_cur,
                                                   float* __restrict__ out,
                                                   int step) {
    int blk = blockIdx.x;
    int dir = blk >> 7;
    int gb  = (blk >> 6) & 1;
    int s   = blk & 63;
    int n0  = s * 16;
    int t   = dir ? (T_LEN - 1 - step) : step;

    int w = threadIdx.x >> 6, l = threadIdx.x & 63;
    int lm = l & 15, lq = l >> 4;
    int mrowA = gb * 32 + w * 16 + lm;

    const bf16* Rh_d = Rh + (size_t)dir * BATCH * HDIM;
    const bf16* Wp   = wt_h + (size_t)(dir * 3 + 2) * HDIM * HDIM + (size_t)(n0 + lm) * HDIM + lq * 8;
    const bf16* A    = Rh_d + (size_t)mrowA * HDIM + lq * 8;

    f32x4 acc = {};
#pragma unroll 8
    for (int k = 0; k < HDIM; k += 32) {
        bf16x8 a = *(const bf16x8*)(A + k);
        bf16x8 b = *(const bf16x8*)(Wp + k);
        acc = __builtin_amdgcn_mfma_f32_16x16x32_bf16(a, b, acc, 0, 0, 0);
    }

    bf16* h_d = h_cur + (size_t)dir * BATCH * HDIM;
    const bf16* Z_d = Zbuf + (size_t)dir * BATCH * HDIM;
    const bf16* xp = XP + ((size_t)(dir * 3 + 2) * T_LEN + t) * BATCH * HDIM;
    int n = n0 + lm;
    int brow = gb * 32 + w * 16 + lq * 4;
#pragma unroll
    for (int r = 0; r < 4; r++) {
        int b_ = brow + r;
        float pre = acc[r] + (float)xp[(size_t)b_ * HDIM + n];
        float e2x = __expf(2.0f * pre);
        float ht  = (e2x - 1.0f) / (e2x + 1.0f);
        float z   = (float)Z_d[(size_t)b_ * HDIM + n];
        float ho  = (float)h_d[(size_t)b_ * HDIM + n];
        float hn  = z * ht + (1.0f - z) * ho;
        h_d[(size_t)b_ * HDIM + n] = (bf16)hn;
        out[((size_t)b_ * T_LEN + t) * (2 * HDIM) + (size_t)dir * HDIM + n] = hn;
    }
}

// ---------------------------------------------------------------------------
extern "C" void kernel_launch(void* const* d_in, const int* in_sizes, int n_in,
                              void* d_out, int out_size, void* d_ws, size_t ws_size,
                              hipStream_t stream) {
    const float* x   = (const float*)d_in[0];
    const float* hpf = (const float*)d_in[1];
    const float* hpb = (const float*)d_in[2];

    // Workspace layout (bytes)
    unsigned char* ws = (unsigned char*)d_ws;
    size_t off = 0;
    bf16* wt_h = (bf16*)(ws + off); off += (size_t)6 * HDIM * HDIM * 2;            // 12.58 MB
    bf16* wt_x = (bf16*)(ws + off); off += (size_t)6 * HDIM * IDIM * 2;            // 6.29 MB
    bf16* xbf  = (bf16*)(ws + off); off += (size_t)BATCH * T_LEN * IDIM * 2;       // 33.55 MB
    bf16* XP   = (bf16*)(ws + off); off += (size_t)6 * T_LEN * BATCH * HDIM * 2;   // 402.65 MB
    bf16* h_cur = (bf16*)(ws + off); off += (size_t)2 * BATCH * HDIM * 2;
    bf16* Rh    = (bf16*)(ws + off); off += (size_t)2 * BATCH * HDIM * 2;
    bf16* Zbuf  = (bf16*)(ws + off); off += (size_t)2 * BATCH * HDIM * 2;

    float* out = (float*)d_out;

    // K0: weights transpose+convert
    Ptr12 wp;
    // W_h: hr_f, hz_f, hh_f, hr_b, hz_b, hh_b
    wp.p[0] = (const float*)d_in[3];  wp.p[1] = (const float*)d_in[6];  wp.p[2] = (const float*)d_in[9];
    wp.p[3] = (const float*)d_in[12]; wp.p[4] = (const float*)d_in[15]; wp.p[5] = (const float*)d_in[18];
    // W_x: xr_f, xz_f, xh_f, xr_b, xz_b, xh_b
    wp.p[6] = (const float*)d_in[4];  wp.p[7] = (const float*)d_in[7];  wp.p[8] = (const float*)d_in[10];
    wp.p[9] = (const float*)d_in[13]; wp.p[10] = (const float*)d_in[16]; wp.p[11] = (const float*)d_in[19];
    transpose_convert<<<dim3(32, 32, 12), 256, 0, stream>>>(wp, wt_h, wt_x);

    // K0b: x -> bf16   (64*512*512 / 4 elems per thread / 256 thr)
    convert_x<<<16384, 256, 0, stream>>>(x, xbf);

    // K0c: init h
    init_h<<<256, 256, 0, stream>>>(hpf, hpb, h_cur);

    // K1: xproj
    Ptr6 bp;
    bp.p[0] = (const float*)d_in[5];  bp.p[1] = (const float*)d_in[8];  bp.p[2] = (const float*)d_in[11];
    bp.p[3] = (const float*)d_in[14]; bp.p[4] = (const float*)d_in[17]; bp.p[5] = (const float*)d_in[20];
    xproj_gemm<<<dim3(512, 16, 6), 256, 0, stream>>>(xbf, wt_x, bp, XP);

    // Recurrence: 512 steps x (phase A, phase B)
    for (int step = 0; step < T_LEN; ++step) {
        gru_phase_a<<<256, 256, 0, stream>>>(wt_h, XP, h_cur, Rh, Zbuf, step);
        gru_phase_b<<<256, 128, 0, stream>>>(wt_h, XP, Rh, Zbuf, h_cur, out, step);
    }
}